// Round 8
// baseline (504.581 us; speedup 1.0000x reference)
//
#include <hip/hip_runtime.h>
#include <cstdint>
#include <cstddef>

// ---------------------------------------------------------------------------
// SparseConv3DBlock: BN(inference)+SiLU -> gather(27 neighbors) -> implicit GEMM
// N=200000, F_IN=64, F_OUT=128, K=27.  bf16 MFMA path.
//   k1: y_bf16[N][64] = silu(bn(x))
//   k2: Wt_bf16[27][128][64] = transpose(W)
//   k3: BM=64, 4 waves (256 thr). Wave = (rg,cg) in 2x2: computes 32 rows x
//       64 cols (2rt x 4ct) -> each A ds_read feeds 4 MFMAs (was 1): block
//       LDS-read 384 cyc vs MFMA 621 cyc -> MFMA-dominant (round-7 fix).
//       Depth-1 reg staging (round-5 proven): load A(k+1)->regs at top,
//       MFMA(k), ds_write at bottom, one __syncthreads/phase. XOR swizzle.
//   Round-6 lesson: never set launch_bounds below natural VGPR demand.
// ---------------------------------------------------------------------------

typedef __attribute__((ext_vector_type(8))) short short8;
typedef __attribute__((ext_vector_type(4))) float f32x4;

#define N_VOX 200000
#define F_IN 64
#define F_OUT 128
#define KOFF 27
#define BM 64

__device__ __forceinline__ short f2bf(float f) {
  unsigned u = __builtin_bit_cast(unsigned, f);
  u += 0x7fffu + ((u >> 16) & 1u);   // RNE
  return (short)(u >> 16);
}

// ---------------- Kernel 1: BN + SiLU + cast to bf16 ----------------------
__global__ __launch_bounds__(256) void bn_silu_kernel(
    const float* __restrict__ x, const float* __restrict__ gamma,
    const float* __restrict__ beta, const float* __restrict__ mean,
    const float* __restrict__ var, short* __restrict__ y) {
  __shared__ float s_scale[F_IN], s_bias[F_IN];
  int tid = threadIdx.x;
  if (tid < F_IN) {
    float s = gamma[tid] * rsqrtf(var[tid] + 1e-5f);
    s_scale[tid] = s;
    s_bias[tid] = beta[tid] - mean[tid] * s;
  }
  __syncthreads();
  size_t i = ((size_t)blockIdx.x * 256 + tid) * 8;   // 12.8M total, exact
  int f0 = (int)(i & (F_IN - 1));                    // multiple of 8
  float4 x0 = *(const float4*)(x + i);
  float4 x1 = *(const float4*)(x + i + 4);
  float v[8] = {x0.x, x0.y, x0.z, x0.w, x1.x, x1.y, x1.z, x1.w};
  short8 o;
#pragma unroll
  for (int j = 0; j < 8; ++j) {
    float t = v[j] * s_scale[f0 + j] + s_bias[f0 + j];
    float sg = 1.0f / (1.0f + __expf(-t));
    o[j] = f2bf(t * sg);
  }
  *(short8*)(y + i) = o;
}

// ---------------- Kernel 2: W[27][64][128] f32 -> Wt[27][128][64] bf16 ----
__global__ __launch_bounds__(256) void wprep_kernel(
    const float* __restrict__ W, short* __restrict__ Wt) {
  int tid = blockIdx.x * 256 + threadIdx.x;        // 27*128*8 = 27648 threads
  if (tid >= KOFF * F_OUT * 8) return;
  int k = tid >> 10;                               // /(128*8)
  int r = tid & 1023;
  int o = r >> 3;
  int f0 = (r & 7) * 8;
  short8 vv;
#pragma unroll
  for (int i = 0; i < 8; ++i)
    vv[i] = f2bf(W[((size_t)k * F_IN + f0 + i) * F_OUT + o]);
  *(short8*)(Wt + ((size_t)k * F_OUT + o) * F_IN + f0) = vv;
}

// ---------------- Kernel 3: wide-tile reg-staged gather + implicit GEMM ---
// BM=64 voxels/block, 256 threads = 4 waves. Wave (rg=w>>1, cg=w&1):
// rows rg*32..+32 (2 rt), cols cg*64..+64 (4 ct). 16 MFMA / 4 A-ds_reads
// per phase. Phase k: load A(k+1)->regs, B(k+1)->BNEXT, idx(k+2)->INEXT;
// MFMA(k) from buf[k&1]; ds_write A regs -> buf^1 (swizzled); sync.

__global__ __launch_bounds__(256, 4) void conv_mfma_kernel(
    const short* __restrict__ y,     // [N][64] bf16
    const short* __restrict__ Wt,    // [27][128][64] bf16
    const int* __restrict__ nidx,    // [N][27]
    float* __restrict__ out) {       // [N][128] f32
  __shared__ __align__(16) short Atile[2][BM * F_IN];   // 2 x 8 KB

  const int tid = threadIdx.x;
  const int wave = tid >> 6;         // 0..3
  const int lane = tid & 63;
  const int lhi = lane >> 4;         // 0..3
  const int llo = lane & 15;
  const int rg = wave >> 1;          // row-group: rows rg*32..+32
  const int cg = wave & 1;           // col-group: cols cg*64..+64
  const int row0 = blockIdx.x * BM;  // 200000 = 64*3125: no tail anywhere

  // gather geometry: wave fills rows [16w,16w+16); lane serves m0, m1=m0+8
  const int m0 = wave * 16 + (lane >> 3);
  const int m1 = m0 + 8;
  const int c = lane & 7;            // 16B chunk within 128B row
  // swizzled LDS byte offsets for ds_write (m1&7 == m0&7 -> wr1 = wr0+1024)
  const int wr0 = m0 * 128 + ((c ^ (m0 & 7)) << 4);
  const int wr1 = wr0 + 1024;
  // per-lane idx streams (8 lanes share each address -> HW broadcast)
  const int* ip0 = nidx + (size_t)(row0 + m0) * KOFF;
  const int* ip1 = nidx + (size_t)(row0 + m1) * KOFF;
  // B stream: this wave's col-group slice, per-lane frag base
  const short* wtp = Wt + (size_t)(cg * 64 + llo) * F_IN + lhi * 8;

  f32x4 acc[2][4] = {};
  short8 bA[4][2], bB[4][2];         // B double buffer (static idx via unroll)
  int i_a0, i_a1, i_b0, i_b1;        // idx prefetch regs

  // ---- prologue: A(0) -> buf0; idx(1); B(0) -> bA ----
  {
    const int g0 = ip0[0], g1 = ip1[0];
    short8 t0 = *(const short8*)(y + (size_t)g0 * F_IN + c * 8);
    short8 t1 = *(const short8*)(y + (size_t)g1 * F_IN + c * 8);
    i_a0 = ip0[1];
    i_a1 = ip1[1];
#pragma unroll
    for (int ct = 0; ct < 4; ++ct)
#pragma unroll
      for (int kh = 0; kh < 2; ++kh)
        bA[ct][kh] = *(const short8*)(wtp + ct * 1024 + kh * 32);
    *(short8*)((char*)Atile[0] + wr0) = t0;
    *(short8*)((char*)Atile[0] + wr1) = t1;
  }
  __syncthreads();

  // Phase K: compute buf K&1 with BCUR; stage A(K+1) (addr from IC*),
  // prefetch B(K+1)->BNEXT and idx(K+2)->IN*.
#define CONV_BODY(K, BUF, BCUR, BNEXT, IC0, IC1, IN0, IN1)                     \
  {                                                                            \
    short8 as0, as1;                                                           \
    if ((K) + 2 < KOFF) {                                                      \
      IN0 = ip0[(K) + 2];                                                      \
      IN1 = ip1[(K) + 2];                                                      \
    }                                                                          \
    if ((K) + 1 < KOFF) {                                                      \
      as0 = *(const short8*)(y + (size_t)IC0 * F_IN + c * 8);                  \
      as1 = *(const short8*)(y + (size_t)IC1 * F_IN + c * 8);                  \
      _Pragma("unroll")                                                        \
      for (int ct = 0; ct < 4; ++ct)                                           \
        _Pragma("unroll")                                                      \
        for (int kh = 0; kh < 2; ++kh)                                         \
          (BNEXT)[ct][kh] = *(const short8*)(wtp + (size_t)((K) + 1) * 8192 +  \
                                             ct * 1024 + kh * 32);             \
    }                                                                          \
    __builtin_amdgcn_sched_barrier(0); /* loads issue before MFMA region */    \
    _Pragma("unroll")                                                          \
    for (int rt = 0; rt < 2; ++rt) {                                           \
      const int mm = rg * 32 + rt * 16 + llo;                                  \
      const int base = mm * 128 + lhi * 16;                                    \
      const int swz = (mm & 7) << 4;                                           \
      short8 a0 = *(const short8*)((const char*)Atile[BUF] + (base ^ swz));    \
      short8 a1 =                                                              \
          *(const short8*)((const char*)Atile[BUF] + ((base + 64) ^ swz));     \
      _Pragma("unroll")                                                        \
      for (int ct = 0; ct < 4; ++ct) {                                         \
        acc[rt][ct] = __builtin_amdgcn_mfma_f32_16x16x32_bf16(                 \
            a0, (BCUR)[ct][0], acc[rt][ct], 0, 0, 0);                          \
        acc[rt][ct] = __builtin_amdgcn_mfma_f32_16x16x32_bf16(                 \
            a1, (BCUR)[ct][1], acc[rt][ct], 0, 0, 0);                          \
      }                                                                        \
    }                                                                          \
    __builtin_amdgcn_sched_barrier(0); /* keep ds_writes after MFMAs */        \
    if ((K) + 1 < KOFF) {                                                      \
      *(short8*)((char*)Atile[(BUF) ^ 1] + wr0) = as0;                         \
      *(short8*)((char*)Atile[(BUF) ^ 1] + wr1) = as1;                         \
    }                                                                          \
    __syncthreads();                                                           \
  }

  for (int k = 0; k < KOFF - 1; k += 2) {        // k = 0,2,...,24
    CONV_BODY(k, 0, bA, bB, i_a0, i_a1, i_b0, i_b1);
    CONV_BODY(k + 1, 1, bB, bA, i_b0, i_b1, i_a0, i_a1);
  }
  CONV_BODY(KOFF - 1, 0, bA, bB, i_a0, i_a1, i_b0, i_b1);   // k = 26
#undef CONV_BODY

  // ---- epilogue: C/D layout col=lane&15, row=(lane>>4)*4+j ----
#pragma unroll
  for (int rt = 0; rt < 2; ++rt)
#pragma unroll
    for (int ct = 0; ct < 4; ++ct) {
      const int col = cg * 64 + ct * 16 + llo;
      const int rbase = row0 + rg * 32 + rt * 16 + lhi * 4;
#pragma unroll
      for (int j = 0; j < 4; ++j)
        out[(size_t)(rbase + j) * F_OUT + col] = acc[rt][ct][j];
    }
}

// ---------------------------------------------------------------------------
extern "C" void kernel_launch(void* const* d_in, const int* in_sizes, int n_in,
                              void* d_out, int out_size, void* d_ws, size_t ws_size,
                              hipStream_t stream) {
  const float* x     = (const float*)d_in[0];
  const float* gamma = (const float*)d_in[1];
  const float* beta  = (const float*)d_in[2];
  const float* rmean = (const float*)d_in[3];
  const float* rvar  = (const float*)d_in[4];
  const float* W     = (const float*)d_in[5];
  const int*   nidx  = (const int*)d_in[6];
  float* out = (float*)d_out;

  // workspace layout
  short* y_bf16  = (short*)d_ws;                                      // 25.6 MB
  short* Wt_bf16 = (short*)((char*)d_ws + (size_t)N_VOX * F_IN * 2);  // 442 KB

  bn_silu_kernel<<<(N_VOX * F_IN) / (256 * 8), 256, 0, stream>>>(
      x, gamma, beta, rmean, rvar, y_bf16);

  wprep_kernel<<<(KOFF * F_OUT * 8 + 255) / 256, 256, 0, stream>>>(W, Wt_bf16);

  // 200000 = 64 * 3125: exact grid, no tail.
  conv_mfma_kernel<<<N_VOX / BM, 256, 0, stream>>>(y_bf16, Wt_bf16, nidx, out);
}

// Round 9
// 225.539 us; speedup vs baseline: 2.2372x; 2.2372x over previous
//
#include <hip/hip_runtime.h>
#include <cstdint>
#include <cstddef>

// ---------------------------------------------------------------------------
// SparseConv3DBlock: BN(inference)+SiLU -> gather(27 neighbors) -> implicit GEMM
// N=200000, F_IN=64, F_OUT=128, K=27.  bf16 MFMA path.
//   k1: y_bf16[N][64] = silu(bn(x))
//   k2: Wt_bf16[27][128][64] = transpose(W)
//   k3: BM=128, 8 waves as (rg 2 x cg 4): wave computes 64 rows x 32 cols
//       (4rt x 2ct) -> each A ds_read feeds 2 MFMAs; block LDS-read traffic
//       halves vs r5 (the measured ~88us LDS wall). Depth-1 reg staging
//       (r5-proven): load A(k+1)->regs at top, MFMA(k), ds_write at bottom,
//       one __syncthreads/phase. XOR swizzle on ds_write + ds_read.
//   r6/r8 lesson: keep natural VGPR demand (~95) under the cap (128).
// ---------------------------------------------------------------------------

typedef __attribute__((ext_vector_type(8))) short short8;
typedef __attribute__((ext_vector_type(4))) float f32x4;

#define N_VOX 200000
#define F_IN 64
#define F_OUT 128
#define KOFF 27
#define BM 128

__device__ __forceinline__ short f2bf(float f) {
  unsigned u = __builtin_bit_cast(unsigned, f);
  u += 0x7fffu + ((u >> 16) & 1u);   // RNE
  return (short)(u >> 16);
}

// ---------------- Kernel 1: BN + SiLU + cast to bf16 ----------------------
__global__ __launch_bounds__(256) void bn_silu_kernel(
    const float* __restrict__ x, const float* __restrict__ gamma,
    const float* __restrict__ beta, const float* __restrict__ mean,
    const float* __restrict__ var, short* __restrict__ y) {
  __shared__ float s_scale[F_IN], s_bias[F_IN];
  int tid = threadIdx.x;
  if (tid < F_IN) {
    float s = gamma[tid] * rsqrtf(var[tid] + 1e-5f);
    s_scale[tid] = s;
    s_bias[tid] = beta[tid] - mean[tid] * s;
  }
  __syncthreads();
  size_t i = ((size_t)blockIdx.x * 256 + tid) * 8;   // 12.8M total, exact
  int f0 = (int)(i & (F_IN - 1));                    // multiple of 8
  float4 x0 = *(const float4*)(x + i);
  float4 x1 = *(const float4*)(x + i + 4);
  float v[8] = {x0.x, x0.y, x0.z, x0.w, x1.x, x1.y, x1.z, x1.w};
  short8 o;
#pragma unroll
  for (int j = 0; j < 8; ++j) {
    float t = v[j] * s_scale[f0 + j] + s_bias[f0 + j];
    float sg = 1.0f / (1.0f + __expf(-t));
    o[j] = f2bf(t * sg);
  }
  *(short8*)(y + i) = o;
}

// ---------------- Kernel 2: W[27][64][128] f32 -> Wt[27][128][64] bf16 ----
__global__ __launch_bounds__(256) void wprep_kernel(
    const float* __restrict__ W, short* __restrict__ Wt) {
  int tid = blockIdx.x * 256 + threadIdx.x;        // 27*128*8 = 27648 threads
  if (tid >= KOFF * F_OUT * 8) return;
  int k = tid >> 10;                               // /(128*8)
  int r = tid & 1023;
  int o = r >> 3;
  int f0 = (r & 7) * 8;
  short8 vv;
#pragma unroll
  for (int i = 0; i < 8; ++i)
    vv[i] = f2bf(W[((size_t)k * F_IN + f0 + i) * F_OUT + o]);
  *(short8*)(Wt + ((size_t)k * F_OUT + o) * F_IN + f0) = vv;
}

// ---------------- Kernel 3: 2x4-tile reg-staged gather + implicit GEMM ----
// BM=128 voxels/block, 512 threads = 8 waves. Wave (rg=w>>2, cg=w&3):
// rows rg*64..+64 (4 rt), cols cg*32..+32 (2 ct). 16 MFMA per 8 A-ds_reads
// per phase. Phase k: load A(k+1)->regs + B(k+1)->BNEXT; MFMA(k) from
// buf[k&1]; ds_write A regs -> buf^1 (swizzled); one __syncthreads.

__global__ __launch_bounds__(512, 4) void conv_mfma_kernel(
    const short* __restrict__ y,     // [N][64] bf16
    const short* __restrict__ Wt,    // [27][128][64] bf16
    const int* __restrict__ nidx,    // [N][27]
    float* __restrict__ out) {       // [N][128] f32
  __shared__ __align__(16) short Atile[2][BM * F_IN];   // 2 x 16 KB
  __shared__ int s_idx[BM * KOFF];                      // 13.5 KB

  const int tid = threadIdx.x;
  const int wave = tid >> 6;         // 0..7
  const int lane = tid & 63;
  const int lhi = lane >> 4;         // 0..3
  const int llo = lane & 15;
  const int rg = wave >> 2;          // row-group: rows rg*64..+64
  const int cg = wave & 3;           // col-group: cols cg*32..+32
  const int row0 = blockIdx.x * BM;
  const int nval = (N_VOX - row0 < BM) ? (N_VOX - row0) : BM;

  // gather geometry (independent of compute mapping): wave fills rows
  // [16w,16w+16); lane serves rows m0, m1=m0+8, 16B chunk c
  const int m0 = wave * 16 + (lane >> 3);
  const int m1 = m0 + 8;
  const int c = lane & 7;
  // swizzled LDS byte offsets for ds_write (m1&7 == m0&7 -> wr1 = wr0+1024)
  const int wr0 = m0 * 128 + ((c ^ (m0 & 7)) << 4);
  const int wr1 = wr0 + 1024;
  // B stream: this wave's col slice, per-lane frag base
  const short* wtp = Wt + (size_t)(cg * 32 + llo) * F_IN + lhi * 8;

  // stage this block's neighbor indices (coalesced); pad tail rows with 0
  for (int i = tid; i < BM * KOFF; i += 512)
    s_idx[i] = (i < nval * KOFF) ? nidx[(size_t)row0 * KOFF + i] : 0;
  __syncthreads();

  f32x4 acc[4][2] = {};
  short8 bA[2][2], bB[2][2];         // B double buffer (static idx via unroll)

  // ---- prologue: A(0) -> buf0; B(0) -> bA ----
  {
    const int g0 = s_idx[m0 * KOFF], g1 = s_idx[m1 * KOFF];
    short8 t0 = *(const short8*)(y + (size_t)g0 * F_IN + c * 8);
    short8 t1 = *(const short8*)(y + (size_t)g1 * F_IN + c * 8);
#pragma unroll
    for (int ct = 0; ct < 2; ++ct)
#pragma unroll
      for (int kh = 0; kh < 2; ++kh)
        bA[ct][kh] = *(const short8*)(wtp + ct * 1024 + kh * 32);
    *(short8*)((char*)Atile[0] + wr0) = t0;
    *(short8*)((char*)Atile[0] + wr1) = t1;
  }
  __syncthreads();

#define CONV_BODY(K, BUF, BCUR, BNEXT)                                         \
  {                                                                            \
    short8 as0, as1;                                                           \
    if ((K) + 1 < KOFF) {                                                      \
      const int g0 = s_idx[m0 * KOFF + (K) + 1];                               \
      const int g1 = s_idx[m1 * KOFF + (K) + 1];                               \
      as0 = *(const short8*)(y + (size_t)g0 * F_IN + c * 8);                   \
      as1 = *(const short8*)(y + (size_t)g1 * F_IN + c * 8);                   \
      _Pragma("unroll")                                                        \
      for (int ct = 0; ct < 2; ++ct)                                           \
        _Pragma("unroll")                                                      \
        for (int kh = 0; kh < 2; ++kh)                                         \
          (BNEXT)[ct][kh] = *(const short8*)(wtp + (size_t)((K) + 1) * 8192 +  \
                                             ct * 1024 + kh * 32);             \
    }                                                                          \
    __builtin_amdgcn_sched_barrier(0); /* loads issue before MFMA region */    \
    _Pragma("unroll")                                                          \
    for (int rt = 0; rt < 4; ++rt) {                                           \
      const int mm = rg * 64 + rt * 16 + llo;                                  \
      const int base = mm * 128 + lhi * 16;                                    \
      const int swz = (mm & 7) << 4;                                           \
      short8 a0 = *(const short8*)((const char*)Atile[BUF] + (base ^ swz));    \
      short8 a1 =                                                              \
          *(const short8*)((const char*)Atile[BUF] + ((base + 64) ^ swz));     \
      _Pragma("unroll")                                                        \
      for (int ct = 0; ct < 2; ++ct) {                                         \
        acc[rt][ct] = __builtin_amdgcn_mfma_f32_16x16x32_bf16(                 \
            a0, (BCUR)[ct][0], acc[rt][ct], 0, 0, 0);                          \
        acc[rt][ct] = __builtin_amdgcn_mfma_f32_16x16x32_bf16(                 \
            a1, (BCUR)[ct][1], acc[rt][ct], 0, 0, 0);                          \
      }                                                                        \
    }                                                                          \
    __builtin_amdgcn_sched_barrier(0); /* keep ds_writes after MFMAs */        \
    if ((K) + 1 < KOFF) {                                                      \
      *(short8*)((char*)Atile[(BUF) ^ 1] + wr0) = as0;                         \
      *(short8*)((char*)Atile[(BUF) ^ 1] + wr1) = as1;                         \
    }                                                                          \
    __syncthreads();                                                           \
  }

  for (int k = 0; k < KOFF - 1; k += 2) {        // k = 0,2,...,24
    CONV_BODY(k, 0, bA, bB);
    CONV_BODY(k + 1, 1, bB, bA);
  }
  CONV_BODY(KOFF - 1, 0, bA, bB);                // k = 26
#undef CONV_BODY

  // ---- epilogue: C/D layout col=lane&15, row=(lane>>4)*4+j ----
#pragma unroll
  for (int rt = 0; rt < 4; ++rt)
#pragma unroll
    for (int ct = 0; ct < 2; ++ct) {
      const int col = cg * 32 + ct * 16 + llo;
      const int rbase = row0 + rg * 64 + rt * 16 + lhi * 4;
#pragma unroll
      for (int j = 0; j < 4; ++j) {
        const int row = rbase + j;
        if (row < N_VOX) out[(size_t)row * F_OUT + col] = acc[rt][ct][j];
      }
    }
}

// ---------------------------------------------------------------------------
extern "C" void kernel_launch(void* const* d_in, const int* in_sizes, int n_in,
                              void* d_out, int out_size, void* d_ws, size_t ws_size,
                              hipStream_t stream) {
  const float* x     = (const float*)d_in[0];
  const float* gamma = (const float*)d_in[1];
  const float* beta  = (const float*)d_in[2];
  const float* rmean = (const float*)d_in[3];
  const float* rvar  = (const float*)d_in[4];
  const float* W     = (const float*)d_in[5];
  const int*   nidx  = (const int*)d_in[6];
  float* out = (float*)d_out;

  // workspace layout
  short* y_bf16  = (short*)d_ws;                                      // 25.6 MB
  short* Wt_bf16 = (short*)((char*)d_ws + (size_t)N_VOX * F_IN * 2);  // 442 KB

  bn_silu_kernel<<<(N_VOX * F_IN) / (256 * 8), 256, 0, stream>>>(
      x, gamma, beta, rmean, rvar, y_bf16);

  wprep_kernel<<<(KOFF * F_OUT * 8 + 255) / 256, 256, 0, stream>>>(W, Wt_bf16);

  conv_mfma_kernel<<<(N_VOX + BM - 1) / BM, 512, 0, stream>>>(
      y_bf16, Wt_bf16, nidx, out);
}